// Round 4
// baseline (446.805 us; speedup 1.0000x reference)
//
#include <hip/hip_runtime.h>
#include <hip/hip_bf16.h>

typedef __attribute__((ext_vector_type(8))) short short8;
typedef __attribute__((ext_vector_type(4))) float f32x4;

__device__ __forceinline__ unsigned short f2bf(float f) {
    __hip_bfloat16 h = __float2bfloat16(f);
    return *reinterpret_cast<unsigned short*>(&h);
}
__device__ __forceinline__ float bf2f(unsigned short u) {
    __hip_bfloat16 h = *reinterpret_cast<__hip_bfloat16*>(&u);
    return __bfloat162float(h);
}
__device__ __forceinline__ void hilo(float f, unsigned short& hi, unsigned short& lo) {
    hi = f2bf(f);
    lo = f2bf(f - bf2f(hi));
}

// ---------------- weight transpose + bf16 convert ----------------
// W [K][N] f32.  MODE 0: out[n*K + k] = bf16(W[k][n])
// MODE 1 (split3 for qkv): out row stride 3K: [n][k]=hi, [n][K+k]=lo, [n][2K+k]=hi
template<int MODE>
__global__ __launch_bounds__(256)
void transpose_w(const float* __restrict__ W, unsigned short* __restrict__ out, int K, int N) {
    __shared__ float tile[32][33];
    const int n0 = blockIdx.x * 32, k0 = blockIdx.y * 32;
    const int tid = threadIdx.x;
    const int r = tid >> 3, c4 = (tid & 7) << 2;
    float4 v = *reinterpret_cast<const float4*>(W + (size_t)(k0 + r) * N + n0 + c4);
    tile[r][c4 + 0] = v.x; tile[r][c4 + 1] = v.y;
    tile[r][c4 + 2] = v.z; tile[r][c4 + 3] = v.w;
    __syncthreads();
    const int n = n0 + r;
    if (MODE == 0) {
        ushort4 o;
        o.x = f2bf(tile[c4 + 0][r]); o.y = f2bf(tile[c4 + 1][r]);
        o.z = f2bf(tile[c4 + 2][r]); o.w = f2bf(tile[c4 + 3][r]);
        *reinterpret_cast<ushort4*>(out + (size_t)n * K + k0 + c4) = o;
    } else {
        ushort4 oh, ol;
        unsigned short hi, lo;
        hilo(tile[c4 + 0][r], hi, lo); oh.x = hi; ol.x = lo;
        hilo(tile[c4 + 1][r], hi, lo); oh.y = hi; ol.y = lo;
        hilo(tile[c4 + 2][r], hi, lo); oh.z = hi; ol.z = lo;
        hilo(tile[c4 + 3][r], hi, lo); oh.w = hi; ol.w = lo;
        size_t base = (size_t)n * 3 * K + k0 + c4;
        *reinterpret_cast<ushort4*>(out + base)         = oh;
        *reinterpret_cast<ushort4*>(out + base + K)     = ol;
        *reinterpret_cast<ushort4*>(out + base + 2 * K) = oh;
    }
}

// ---------------- LayerNorm ----------------
// MODE 0: out [row][1024] bf16.  MODE 1: out [row][3072]: hi, hi, lo (split3 A-layout)
template<int MODE>
__global__ __launch_bounds__(256)
void ln_kernel(const float* __restrict__ x, const float* __restrict__ gw,
               const float* __restrict__ bw, unsigned short* __restrict__ out) {
    const int row = blockIdx.x, tid = threadIdx.x;
    const float* xr = x + (size_t)row * 1024;
    float4 v = *reinterpret_cast<const float4*>(xr + tid * 4);
    float s = v.x + v.y + v.z + v.w;
    float sq = v.x * v.x + v.y * v.y + v.z * v.z + v.w * v.w;
    #pragma unroll
    for (int off = 1; off < 64; off <<= 1) {
        s  += __shfl_xor(s, off);
        sq += __shfl_xor(sq, off);
    }
    __shared__ float ps[4], pq[4];
    const int wave = tid >> 6;
    if ((tid & 63) == 0) { ps[wave] = s; pq[wave] = sq; }
    __syncthreads();
    s  = ps[0] + ps[1] + ps[2] + ps[3];
    sq = pq[0] + pq[1] + pq[2] + pq[3];
    const float mu = s * (1.0f / 1024.0f);
    const float var = sq * (1.0f / 1024.0f) - mu * mu;
    const float rs = rsqrtf(var + 1e-5f);
    float4 gv = *reinterpret_cast<const float4*>(gw + tid * 4);
    float4 bv = *reinterpret_cast<const float4*>(bw + tid * 4);
    float y[4];
    y[0] = (v.x - mu) * rs * gv.x + bv.x;
    y[1] = (v.y - mu) * rs * gv.y + bv.y;
    y[2] = (v.z - mu) * rs * gv.z + bv.z;
    y[3] = (v.w - mu) * rs * gv.w + bv.w;
    if (MODE == 0) {
        ushort4 o;
        o.x = f2bf(y[0]); o.y = f2bf(y[1]); o.z = f2bf(y[2]); o.w = f2bf(y[3]);
        *reinterpret_cast<ushort4*>(out + (size_t)row * 1024 + tid * 4) = o;
    } else {
        ushort4 oh, ol;
        unsigned short hi, lo;
        hilo(y[0], hi, lo); oh.x = hi; ol.x = lo;
        hilo(y[1], hi, lo); oh.y = hi; ol.y = lo;
        hilo(y[2], hi, lo); oh.z = hi; ol.z = lo;
        hilo(y[3], hi, lo); oh.w = hi; ol.w = lo;
        size_t base = (size_t)row * 3072 + tid * 4;
        *reinterpret_cast<ushort4*>(out + base)        = oh;
        *reinterpret_cast<ushort4*>(out + base + 1024) = oh;
        *reinterpret_cast<ushort4*>(out + base + 2048) = ol;
    }
}

// ---------------- GEMM: C = A @ B^T-input + bias (+epilogue) ----------------
// A [M][K] bf16 row-major, Bt [N][K] bf16 row-major. 128x128 tile, BK=32, 4 waves.
// EPI 0: f32 = acc+bias ; EPI 1: f32 = acc+bias+resid ; EPI 2: bf16 = gelu(acc+bias)
template<int EPI>
__global__ __launch_bounds__(256)
void gemm_bt(const unsigned short* __restrict__ A, const unsigned short* __restrict__ Bt,
             const float* __restrict__ bias, const float* resid,
             void* Cout, int M, int N, int K) {
    __shared__ unsigned short As[128][56];
    __shared__ unsigned short Bs[128][56];
    const int tid = threadIdx.x;
    const int wave = tid >> 6, lane = tid & 63;
    const int bm = blockIdx.y << 7, bn = blockIdx.x << 7;
    const int wr = (wave >> 1) << 6, wc = (wave & 1) << 6;
    const int fr = lane & 15, g8 = (lane >> 4) << 3, fq = (lane >> 4) << 2;
    const int sr = tid >> 2, sc = (tid & 3) << 3;
    const unsigned short* Ar0 = A + (size_t)(bm + sr) * K + sc;
    const unsigned short* Ar1 = Ar0 + (size_t)64 * K;
    const unsigned short* Br0 = Bt + (size_t)(bn + sr) * K + sc;
    const unsigned short* Br1 = Br0 + (size_t)64 * K;

    f32x4 acc[4][4];
    #pragma unroll
    for (int m = 0; m < 4; ++m)
        #pragma unroll
        for (int n = 0; n < 4; ++n)
            #pragma unroll
            for (int r = 0; r < 4; ++r) acc[m][n][r] = 0.0f;

    for (int k0 = 0; k0 < K; k0 += 32) {
        __syncthreads();
        *reinterpret_cast<short8*>(&As[sr][sc])      = *reinterpret_cast<const short8*>(Ar0 + k0);
        *reinterpret_cast<short8*>(&As[sr + 64][sc]) = *reinterpret_cast<const short8*>(Ar1 + k0);
        *reinterpret_cast<short8*>(&Bs[sr][sc])      = *reinterpret_cast<const short8*>(Br0 + k0);
        *reinterpret_cast<short8*>(&Bs[sr + 64][sc]) = *reinterpret_cast<const short8*>(Br1 + k0);
        __syncthreads();
        short8 af[4], bfv[4];
        #pragma unroll
        for (int m = 0; m < 4; ++m)
            af[m] = *reinterpret_cast<const short8*>(&As[wr + m * 16 + fr][g8]);
        #pragma unroll
        for (int n = 0; n < 4; ++n)
            bfv[n] = *reinterpret_cast<const short8*>(&Bs[wc + n * 16 + fr][g8]);
        #pragma unroll
        for (int m = 0; m < 4; ++m)
            #pragma unroll
            for (int n = 0; n < 4; ++n)
                acc[m][n] = __builtin_amdgcn_mfma_f32_16x16x32_bf16(af[m], bfv[n], acc[m][n], 0, 0, 0);
    }

    #pragma unroll
    for (int n = 0; n < 4; ++n) {
        const int col = bn + wc + n * 16 + fr;
        const float bc = bias[col];
        #pragma unroll
        for (int m = 0; m < 4; ++m) {
            #pragma unroll
            for (int r = 0; r < 4; ++r) {
                const int row = bm + wr + m * 16 + fq + r;
                const size_t idx = (size_t)row * N + col;
                float v = acc[m][n][r] + bc;
                if (EPI == 0) {
                    reinterpret_cast<float*>(Cout)[idx] = v;
                } else if (EPI == 1) {
                    reinterpret_cast<float*>(Cout)[idx] = v + resid[idx];
                } else {
                    float ge = 0.5f * v * (1.0f + erff(v * 0.70710678118654752f));
                    reinterpret_cast<unsigned short*>(Cout)[idx] = f2bf(ge);
                }
            }
        }
    }
}

// ---------------- Flash attention ----------------
// qkv f32 [4096][3072] (row: [q(16*64) | k(16*64) | v(16*64)]), ctx bf16 [4096][1024]
// scores = (q . k) * 8  (reference multiplies by sqrt(dk)!)
// Split precision QK^T: S = qhi.khi + qhi.klo + qlo.khi
__global__ __launch_bounds__(256)
void attn_kernel(const float* __restrict__ qkv, unsigned short* __restrict__ ctx) {
    __shared__ unsigned short Khi[64][72];
    __shared__ unsigned short Klo[64][72];
    __shared__ unsigned short Vt[64][72];
    __shared__ unsigned short Plds[4][16][72];
    const int qt = blockIdx.x;          // 16 q-tiles of 64 rows
    const int bh = blockIdx.y;          // b*16 + h
    const int b = bh >> 4, h = bh & 15;
    const int tid = threadIdx.x;
    const int wave = tid >> 6, lane = tid & 63;
    const int fr = lane & 15, g8 = (lane >> 4) << 3, fq = (lane >> 4) << 2;

    // Q fragments in registers (hi/lo, 2 k-steps over dk=64)
    const int qrow = qt * 64 + wave * 16 + fr;
    const float* qp = qkv + ((size_t)(b * 1024 + qrow)) * 3072 + h * 64;
    short8 qhi[2], qlo[2];
    #pragma unroll
    for (int s_ = 0; s_ < 2; ++s_) {
        #pragma unroll
        for (int j = 0; j < 8; ++j) {
            float f = qp[s_ * 32 + g8 + j];
            unsigned short hi = f2bf(f);
            qhi[s_][j] = (short)hi;
            qlo[s_][j] = (short)f2bf(f - bf2f(hi));
        }
    }

    float mrun[4], lrun[4];
    f32x4 cacc[4];
    #pragma unroll
    for (int r = 0; r < 4; ++r) { mrun[r] = -3.0e38f; lrun[r] = 0.0f; }
    #pragma unroll
    for (int nd = 0; nd < 4; ++nd)
        #pragma unroll
        for (int r = 0; r < 4; ++r) cacc[nd][r] = 0.0f;

    const int skey = tid >> 2, sd = (tid & 3) << 4;
    const float* kvbase = qkv + ((size_t)(b * 1024 + skey)) * 3072 + h * 64 + sd;

    for (int kt = 0; kt < 16; ++kt) {
        __syncthreads();
        // stage K (hi/lo) and V^T for keys kt*64..+63
        const float* kp = kvbase + (size_t)kt * 64 * 3072;
        #pragma unroll
        for (int j = 0; j < 16; j += 4) {
            float4 kv4 = *reinterpret_cast<const float4*>(kp + 1024 + j);
            float4 vv4 = *reinterpret_cast<const float4*>(kp + 2048 + j);
            float ks[4] = {kv4.x, kv4.y, kv4.z, kv4.w};
            float vs[4] = {vv4.x, vv4.y, vv4.z, vv4.w};
            #pragma unroll
            for (int c = 0; c < 4; ++c) {
                unsigned short hi = f2bf(ks[c]);
                Khi[skey][sd + j + c] = hi;
                Klo[skey][sd + j + c] = f2bf(ks[c] - bf2f(hi));
                Vt[sd + j + c][skey] = f2bf(vs[c]);
            }
        }
        __syncthreads();

        short8 kh[2][4], kl[2][4];
        #pragma unroll
        for (int s_ = 0; s_ < 2; ++s_)
            #pragma unroll
            for (int n = 0; n < 4; ++n) {
                kh[s_][n] = *reinterpret_cast<const short8*>(&Khi[n * 16 + fr][s_ * 32 + g8]);
                kl[s_][n] = *reinterpret_cast<const short8*>(&Klo[n * 16 + fr][s_ * 32 + g8]);
            }
        f32x4 S[4];
        #pragma unroll
        for (int n = 0; n < 4; ++n)
            #pragma unroll
            for (int r = 0; r < 4; ++r) S[n][r] = 0.0f;
        #pragma unroll
        for (int s_ = 0; s_ < 2; ++s_)
            #pragma unroll
            for (int n = 0; n < 4; ++n)
                S[n] = __builtin_amdgcn_mfma_f32_16x16x32_bf16(qhi[s_], kh[s_][n], S[n], 0, 0, 0);
        #pragma unroll
        for (int s_ = 0; s_ < 2; ++s_)
            #pragma unroll
            for (int n = 0; n < 4; ++n)
                S[n] = __builtin_amdgcn_mfma_f32_16x16x32_bf16(qhi[s_], kl[s_][n], S[n], 0, 0, 0);
        #pragma unroll
        for (int s_ = 0; s_ < 2; ++s_)
            #pragma unroll
            for (int n = 0; n < 4; ++n)
                S[n] = __builtin_amdgcn_mfma_f32_16x16x32_bf16(qlo[s_], kh[s_][n], S[n], 0, 0, 0);

        // online softmax: lane holds rows fq+r, cols n*16 + fr (per D-layout)
        float mt[4];
        #pragma unroll
        for (int r = 0; r < 4; ++r)
            mt[r] = fmaxf(fmaxf(S[0][r], S[1][r]), fmaxf(S[2][r], S[3][r])) * 8.0f;
        #pragma unroll
        for (int r = 0; r < 4; ++r) {
            mt[r] = fmaxf(mt[r], __shfl_xor(mt[r], 1));
            mt[r] = fmaxf(mt[r], __shfl_xor(mt[r], 2));
            mt[r] = fmaxf(mt[r], __shfl_xor(mt[r], 4));
            mt[r] = fmaxf(mt[r], __shfl_xor(mt[r], 8));
        }
        float P[4][4], rsum[4];
        #pragma unroll
        for (int r = 0; r < 4; ++r) {
            float mnew = fmaxf(mrun[r], mt[r]);
            float sf = __expf(mrun[r] - mnew);
            mrun[r] = mnew;
            rsum[r] = 0.0f;
            #pragma unroll
            for (int n = 0; n < 4; ++n) {
                float p = __expf(S[n][r] * 8.0f - mnew);
                P[n][r] = p;
                rsum[r] += p;
            }
            lrun[r] *= sf;
            #pragma unroll
            for (int nd = 0; nd < 4; ++nd) cacc[nd][r] *= sf;
        }
        #pragma unroll
        for (int r = 0; r < 4; ++r) {
            rsum[r] += __shfl_xor(rsum[r], 1);
            rsum[r] += __shfl_xor(rsum[r], 2);
            rsum[r] += __shfl_xor(rsum[r], 4);
            rsum[r] += __shfl_xor(rsum[r], 8);
            lrun[r] += rsum[r];
        }
        // P -> LDS (re-fragment for PV A-operand)
        #pragma unroll
        for (int n = 0; n < 4; ++n)
            #pragma unroll
            for (int r = 0; r < 4; ++r)
                Plds[wave][fq + r][n * 16 + fr] = f2bf(P[n][r]);
        __syncthreads();
        // PV: ctx += P @ V
        #pragma unroll
        for (int s_ = 0; s_ < 2; ++s_) {
            short8 pa = *reinterpret_cast<const short8*>(&Plds[wave][fr][s_ * 32 + g8]);
            #pragma unroll
            for (int nd = 0; nd < 4; ++nd) {
                short8 vb = *reinterpret_cast<const short8*>(&Vt[nd * 16 + fr][s_ * 32 + g8]);
                cacc[nd] = __builtin_amdgcn_mfma_f32_16x16x32_bf16(pa, vb, cacc[nd], 0, 0, 0);
            }
        }
    }
    // epilogue: ctx = cacc / l
    #pragma unroll
    for (int r = 0; r < 4; ++r) {
        const float inv = 1.0f / lrun[r];
        const int row = qt * 64 + wave * 16 + fq + r;
        unsigned short* cp = ctx + ((size_t)(b * 1024 + row)) * 1024 + h * 64;
        #pragma unroll
        for (int nd = 0; nd < 4; ++nd)
            cp[nd * 16 + fr] = f2bf(cacc[nd][r] * inv);
    }
}

// ---------------- launch ----------------
extern "C" void kernel_launch(void* const* d_in, const int* in_sizes, int n_in,
                              void* d_out, int out_size, void* d_ws, size_t ws_size,
                              hipStream_t stream) {
    const float* x      = (const float*)d_in[0];
    const float* norm_g = (const float*)d_in[1];
    const float* norm_b = (const float*)d_in[2];
    const float* w_qkv  = (const float*)d_in[3];
    const float* b_qkv  = (const float*)d_in[4];
    const float* w_proj = (const float*)d_in[5];
    const float* b_proj = (const float*)d_in[6];
    const float* w_fc1  = (const float*)d_in[7];
    const float* b_fc1  = (const float*)d_in[8];
    const float* w_fc2  = (const float*)d_in[9];
    const float* b_fc2  = (const float*)d_in[10];
    float* out = (float*)d_out;
    char* ws = (char*)d_ws;

    // workspace layout (~122 MB, with dead-buffer overlap in region G)
    size_t off = 0;
    unsigned short* wqkvT3 = (unsigned short*)(ws + off); off += (size_t)3072 * 3072 * 2;
    unsigned short* wprojT = (unsigned short*)(ws + off); off += (size_t)1024 * 1024 * 2;
    unsigned short* wfc1T  = (unsigned short*)(ws + off); off += (size_t)4096 * 1024 * 2;
    unsigned short* wfc2T  = (unsigned short*)(ws + off); off += (size_t)1024 * 4096 * 2;
    unsigned short* ctxb   = (unsigned short*)(ws + off); off += (size_t)4096 * 1024 * 2;
    char* G = ws + off;
    unsigned short* h3    = (unsigned short*)G;                     // [4096][3072], dead after qkv GEMM
    float*          qkvf  = (float*)(G + (size_t)25165824);         // [4096][3072] f32, dead after attn
    unsigned short* fc1o  = (unsigned short*)G;                     // [4096][4096], overlaps h3+qkv head
    unsigned short* h2    = (unsigned short*)(G + (size_t)33554432);// [4096][1024], overlaps qkv tail

    // weight prep
    transpose_w<1><<<dim3(96, 32),  256, 0, stream>>>(w_qkv,  wqkvT3, 1024, 3072);
    transpose_w<0><<<dim3(32, 32),  256, 0, stream>>>(w_proj, wprojT, 1024, 1024);
    transpose_w<0><<<dim3(128, 32), 256, 0, stream>>>(w_fc1,  wfc1T,  1024, 4096);
    transpose_w<0><<<dim3(32, 128), 256, 0, stream>>>(w_fc2,  wfc2T,  4096, 1024);

    // h = LN(x) (split3) ; qkv = h @ w_qkv + b  (split-precision via K'=3072)
    ln_kernel<1><<<4096, 256, 0, stream>>>(x, norm_g, norm_b, h3);
    gemm_bt<0><<<dim3(24, 32), 256, 0, stream>>>(h3, wqkvT3, b_qkv, nullptr, qkvf, 4096, 3072, 3072);

    // attention -> ctx (bf16)
    attn_kernel<<<dim3(16, 64), 256, 0, stream>>>(qkvf, ctxb);

    // x1 = x + ctx @ w_proj + b   (x1 lives in d_out)
    gemm_bt<1><<<dim3(8, 32), 256, 0, stream>>>(ctxb, wprojT, b_proj, x, out, 4096, 1024, 1024);

    // h2 = LN(x1) ; fc1 = gelu(h2 @ w_fc1 + b) ; out = x1 + fc1 @ w_fc2 + b (in-place)
    ln_kernel<0><<<4096, 256, 0, stream>>>(out, norm_g, norm_b, h2);
    gemm_bt<2><<<dim3(32, 32), 256, 0, stream>>>(h2, wfc1T, b_fc1, nullptr, fc1o, 4096, 4096, 1024);
    gemm_bt<1><<<dim3(8, 32), 256, 0, stream>>>(fc1o, wfc2T, b_fc2, out, out, 4096, 1024, 4096);
}

// Round 5
// 436.544 us; speedup vs baseline: 1.0235x; 1.0235x over previous
//
#include <hip/hip_runtime.h>
#include <hip/hip_bf16.h>

typedef __attribute__((ext_vector_type(8))) short short8;
typedef __attribute__((ext_vector_type(4))) float f32x4;

__device__ __forceinline__ unsigned short f2bf(float f) {
    __hip_bfloat16 h = __float2bfloat16(f);
    return *reinterpret_cast<unsigned short*>(&h);
}
__device__ __forceinline__ float bf2f(unsigned short u) {
    __hip_bfloat16 h = *reinterpret_cast<__hip_bfloat16*>(&u);
    return __bfloat162float(h);
}
__device__ __forceinline__ void hilo(float f, unsigned short& hi, unsigned short& lo) {
    hi = f2bf(f);
    lo = f2bf(f - bf2f(hi));
}

// async global->LDS, 16B per lane, wave-uniform LDS base + lane*16 dest
__device__ __forceinline__ void gld_lds16(const unsigned short* g, unsigned short* l) {
    __builtin_amdgcn_global_load_lds(
        (const __attribute__((address_space(1))) unsigned int*)g,
        (__attribute__((address_space(3))) unsigned int*)l, 16, 0, 0);
}

// ---------------- weight transpose + bf16 convert ----------------
// W [K][N] f32.  MODE 0: out[n*K + k] = bf16(W[k][n])
// MODE 1 (split3 for qkv): out row stride 3K: [n][k]=hi, [n][K+k]=lo, [n][2K+k]=hi
template<int MODE>
__global__ __launch_bounds__(256)
void transpose_w(const float* __restrict__ W, unsigned short* __restrict__ out, int K, int N) {
    __shared__ float tile[32][33];
    const int n0 = blockIdx.x * 32, k0 = blockIdx.y * 32;
    const int tid = threadIdx.x;
    const int r = tid >> 3, c4 = (tid & 7) << 2;
    float4 v = *reinterpret_cast<const float4*>(W + (size_t)(k0 + r) * N + n0 + c4);
    tile[r][c4 + 0] = v.x; tile[r][c4 + 1] = v.y;
    tile[r][c4 + 2] = v.z; tile[r][c4 + 3] = v.w;
    __syncthreads();
    const int n = n0 + r;
    if (MODE == 0) {
        ushort4 o;
        o.x = f2bf(tile[c4 + 0][r]); o.y = f2bf(tile[c4 + 1][r]);
        o.z = f2bf(tile[c4 + 2][r]); o.w = f2bf(tile[c4 + 3][r]);
        *reinterpret_cast<ushort4*>(out + (size_t)n * K + k0 + c4) = o;
    } else {
        ushort4 oh, ol;
        unsigned short hi, lo;
        hilo(tile[c4 + 0][r], hi, lo); oh.x = hi; ol.x = lo;
        hilo(tile[c4 + 1][r], hi, lo); oh.y = hi; ol.y = lo;
        hilo(tile[c4 + 2][r], hi, lo); oh.z = hi; ol.z = lo;
        hilo(tile[c4 + 3][r], hi, lo); oh.w = hi; ol.w = lo;
        size_t base = (size_t)n * 3 * K + k0 + c4;
        *reinterpret_cast<ushort4*>(out + base)         = oh;
        *reinterpret_cast<ushort4*>(out + base + K)     = ol;
        *reinterpret_cast<ushort4*>(out + base + 2 * K) = oh;
    }
}

// ---------------- LayerNorm ----------------
// MODE 0: out [row][1024] bf16.  MODE 1: out [row][3072]: hi, hi, lo (split3 A-layout)
template<int MODE>
__global__ __launch_bounds__(256)
void ln_kernel(const float* __restrict__ x, const float* __restrict__ gw,
               const float* __restrict__ bw, unsigned short* __restrict__ out) {
    const int row = blockIdx.x, tid = threadIdx.x;
    const float* xr = x + (size_t)row * 1024;
    float4 v = *reinterpret_cast<const float4*>(xr + tid * 4);
    float s = v.x + v.y + v.z + v.w;
    float sq = v.x * v.x + v.y * v.y + v.z * v.z + v.w * v.w;
    #pragma unroll
    for (int off = 1; off < 64; off <<= 1) {
        s  += __shfl_xor(s, off);
        sq += __shfl_xor(sq, off);
    }
    __shared__ float ps[4], pq[4];
    const int wave = tid >> 6;
    if ((tid & 63) == 0) { ps[wave] = s; pq[wave] = sq; }
    __syncthreads();
    s  = ps[0] + ps[1] + ps[2] + ps[3];
    sq = pq[0] + pq[1] + pq[2] + pq[3];
    const float mu = s * (1.0f / 1024.0f);
    const float var = sq * (1.0f / 1024.0f) - mu * mu;
    const float rs = rsqrtf(var + 1e-5f);
    float4 gv = *reinterpret_cast<const float4*>(gw + tid * 4);
    float4 bv = *reinterpret_cast<const float4*>(bw + tid * 4);
    float y[4];
    y[0] = (v.x - mu) * rs * gv.x + bv.x;
    y[1] = (v.y - mu) * rs * gv.y + bv.y;
    y[2] = (v.z - mu) * rs * gv.z + bv.z;
    y[3] = (v.w - mu) * rs * gv.w + bv.w;
    if (MODE == 0) {
        ushort4 o;
        o.x = f2bf(y[0]); o.y = f2bf(y[1]); o.z = f2bf(y[2]); o.w = f2bf(y[3]);
        *reinterpret_cast<ushort4*>(out + (size_t)row * 1024 + tid * 4) = o;
    } else {
        ushort4 oh, ol;
        unsigned short hi, lo;
        hilo(y[0], hi, lo); oh.x = hi; ol.x = lo;
        hilo(y[1], hi, lo); oh.y = hi; ol.y = lo;
        hilo(y[2], hi, lo); oh.z = hi; ol.z = lo;
        hilo(y[3], hi, lo); oh.w = hi; ol.w = lo;
        size_t base = (size_t)row * 3072 + tid * 4;
        *reinterpret_cast<ushort4*>(out + base)        = oh;
        *reinterpret_cast<ushort4*>(out + base + 1024) = oh;
        *reinterpret_cast<ushort4*>(out + base + 2048) = ol;
    }
}

// ---------------- GEMM: C = A @ B^T-input + bias (+epilogue) ----------------
// A [M][lda] bf16 row-major (use cols 0..K), Bt [N][ldb] bf16 row-major.
// 128x128 tile, BK=32, 4 waves, global_load_lds staging into LINEAR LDS (m97 structure).
// EPI 0: f32 = acc+bias ; EPI 1: f32 = acc+bias+resid ; EPI 2: bf16 = gelu(acc+bias)
template<int EPI>
__global__ __launch_bounds__(256)
void gemm_bt(const unsigned short* __restrict__ A, const unsigned short* __restrict__ Bt,
             const float* __restrict__ bias, const float* resid,
             void* Cout, int M, int N, int K, int lda, int ldb, int ldc) {
    __shared__ unsigned short As[128 * 32];   // row r at As[r*32], linear (required by global_load_lds)
    __shared__ unsigned short Bs[128 * 32];
    const int tid = threadIdx.x;
    const int wave = tid >> 6, lane = tid & 63;
    const int bm = blockIdx.y << 7, bn = blockIdx.x << 7;
    const int wr = (wave >> 1) << 6, wc = (wave & 1) << 6;
    const int fr = lane & 15, g8 = (lane >> 4) << 3, fq = (lane >> 4) << 2;

    // staging map: wave w covers rows [w*32, w*32+32); per issue (16 rows = 1KB),
    // HW writes lds_base + lane*16B -> row w*32+i*16+(lane>>2), col-short (lane&3)*8.
    const int srow = (wave << 5) + (lane >> 2);
    const int scol = (lane & 3) << 3;
    const unsigned short* gA0 = A + (size_t)(bm + srow) * lda + scol;
    const unsigned short* gA1 = gA0 + (size_t)16 * lda;
    const unsigned short* gB0 = Bt + (size_t)(bn + srow) * ldb + scol;
    const unsigned short* gB1 = gB0 + (size_t)16 * ldb;
    unsigned short* lA = As + (wave << 10);   // wave-uniform base
    unsigned short* lB = Bs + (wave << 10);

    f32x4 acc[4][4];
    #pragma unroll
    for (int m = 0; m < 4; ++m)
        #pragma unroll
        for (int n = 0; n < 4; ++n)
            #pragma unroll
            for (int r = 0; r < 4; ++r) acc[m][n][r] = 0.0f;

    for (int k0 = 0; k0 < K; k0 += 32) {
        __syncthreads();
        gld_lds16(gA0 + k0, lA);
        gld_lds16(gA1 + k0, lA + 512);
        gld_lds16(gB0 + k0, lB);
        gld_lds16(gB1 + k0, lB + 512);
        __syncthreads();   // compiler drains vmcnt(0) before s_barrier
        short8 af[4], bfv[4];
        #pragma unroll
        for (int m = 0; m < 4; ++m)
            af[m] = *reinterpret_cast<const short8*>(&As[(wr + m * 16 + fr) * 32 + g8]);
        #pragma unroll
        for (int n = 0; n < 4; ++n)
            bfv[n] = *reinterpret_cast<const short8*>(&Bs[(wc + n * 16 + fr) * 32 + g8]);
        #pragma unroll
        for (int m = 0; m < 4; ++m)
            #pragma unroll
            for (int n = 0; n < 4; ++n)
                acc[m][n] = __builtin_amdgcn_mfma_f32_16x16x32_bf16(af[m], bfv[n], acc[m][n], 0, 0, 0);
    }

    #pragma unroll
    for (int n = 0; n < 4; ++n) {
        const int col = bn + wc + n * 16 + fr;
        const float bc = bias[col];
        #pragma unroll
        for (int m = 0; m < 4; ++m) {
            #pragma unroll
            for (int r = 0; r < 4; ++r) {
                const int row = bm + wr + m * 16 + fq + r;
                const size_t idx = (size_t)row * ldc + col;
                float v = acc[m][n][r] + bc;
                if (EPI == 0) {
                    reinterpret_cast<float*>(Cout)[idx] = v;
                } else if (EPI == 1) {
                    reinterpret_cast<float*>(Cout)[idx] = v + resid[idx];
                } else {
                    float ge = 0.5f * v * (1.0f + erff(v * 0.70710678118654752f));
                    reinterpret_cast<unsigned short*>(Cout)[idx] = f2bf(ge);
                }
            }
        }
    }
}

// ---------------- K/V pre-conversion ----------------
// qkv f32 [4096][3072] -> Khi/Klo [bh=64][key=1024][d=64] bf16, Vt [bh=64][d=64][key=1024] bf16
// One-shot: removes the 16x-redundant per-q-tile f32->hi/lo conversion in attn.
__global__ __launch_bounds__(256)
void kv_conv(const float* __restrict__ qkv, unsigned short* __restrict__ Khi_g,
             unsigned short* __restrict__ Klo_g, unsigned short* __restrict__ Vt_g) {
    __shared__ unsigned short VtT[64][72];
    const int kc = blockIdx.x;   // 16 chunks of 64 keys
    const int bh = blockIdx.y;   // b*16 + h
    const int b = bh >> 4, h = bh & 15;
    const int tid = threadIdx.x;
    const int key = tid >> 2, c16 = (tid & 3) << 4;
    const float* kp = qkv + ((size_t)(b * 1024 + kc * 64 + key)) * 3072 + h * 64 + c16;
    alignas(16) unsigned short khbuf[16], klbuf[16];
    #pragma unroll
    for (int j = 0; j < 16; j += 4) {
        float4 kv4 = *reinterpret_cast<const float4*>(kp + 1024 + j);
        float4 vv4 = *reinterpret_cast<const float4*>(kp + 2048 + j);
        float ks[4] = {kv4.x, kv4.y, kv4.z, kv4.w};
        float vs[4] = {vv4.x, vv4.y, vv4.z, vv4.w};
        #pragma unroll
        for (int c = 0; c < 4; ++c) {
            unsigned short hi, lo;
            hilo(ks[c], hi, lo);
            khbuf[j + c] = hi; klbuf[j + c] = lo;
            VtT[c16 + j + c][key] = f2bf(vs[c]);
        }
    }
    const size_t kb = ((size_t)bh * 1024 + kc * 64 + key) * 64 + c16;
    *reinterpret_cast<short8*>(Khi_g + kb)     = *reinterpret_cast<short8*>(&khbuf[0]);
    *reinterpret_cast<short8*>(Khi_g + kb + 8) = *reinterpret_cast<short8*>(&khbuf[8]);
    *reinterpret_cast<short8*>(Klo_g + kb)     = *reinterpret_cast<short8*>(&klbuf[0]);
    *reinterpret_cast<short8*>(Klo_g + kb + 8) = *reinterpret_cast<short8*>(&klbuf[8]);
    __syncthreads();
    const int d = tid >> 2;
    const size_t vb = ((size_t)bh * 64 + d) * 1024 + (size_t)kc * 64 + c16;
    *reinterpret_cast<short8*>(Vt_g + vb)     = *reinterpret_cast<const short8*>(&VtT[d][c16]);
    *reinterpret_cast<short8*>(Vt_g + vb + 8) = *reinterpret_cast<const short8*>(&VtT[d][c16 + 8]);
}

// ---------------- Flash attention ----------------
// q from qkvf f32 (hi/lo in reg), K/V from pre-converted bf16 buffers.
// scores = (q . k) * 8  (reference multiplies by sqrt(dk)!)
// Split precision QK^T: S = qhi.khi + qhi.klo + qlo.khi
__global__ __launch_bounds__(256)
void attn_kernel(const float* __restrict__ qkv, const unsigned short* __restrict__ Khi_g,
                 const unsigned short* __restrict__ Klo_g, const unsigned short* __restrict__ Vt_g,
                 unsigned short* __restrict__ ctx) {
    __shared__ unsigned short Khi[64][72];
    __shared__ unsigned short Klo[64][72];
    __shared__ unsigned short Vt[64][72];
    __shared__ unsigned short Plds[4][16][72];
    const int qt = blockIdx.x;          // 16 q-tiles of 64 rows
    const int bh = blockIdx.y;          // b*16 + h
    const int b = bh >> 4, h = bh & 15;
    const int tid = threadIdx.x;
    const int wave = tid >> 6, lane = tid & 63;
    const int fr = lane & 15, g8 = (lane >> 4) << 3, fq = (lane >> 4) << 2;

    // Q fragments in registers (hi/lo, 2 k-steps over dk=64)
    const int qrow = qt * 64 + wave * 16 + fr;
    const float* qp = qkv + ((size_t)(b * 1024 + qrow)) * 3072 + h * 64;
    short8 qhi[2], qlo[2];
    #pragma unroll
    for (int s_ = 0; s_ < 2; ++s_) {
        #pragma unroll
        for (int j = 0; j < 8; ++j) {
            float f = qp[s_ * 32 + g8 + j];
            unsigned short hi = f2bf(f);
            qhi[s_][j] = (short)hi;
            qlo[s_][j] = (short)f2bf(f - bf2f(hi));
        }
    }

    float mrun[4], lrun[4];
    f32x4 cacc[4];
    #pragma unroll
    for (int r = 0; r < 4; ++r) { mrun[r] = -3.0e38f; lrun[r] = 0.0f; }
    #pragma unroll
    for (int nd = 0; nd < 4; ++nd)
        #pragma unroll
        for (int r = 0; r < 4; ++r) cacc[nd][r] = 0.0f;

    const int skey = tid >> 2, sc16 = (tid & 3) << 4;

    for (int kt = 0; kt < 16; ++kt) {
        __syncthreads();
        // stage K(hi/lo) and V^T tiles: vectorized bf16 loads, no conversion
        {
            const size_t kb = ((size_t)bh * 1024 + kt * 64 + skey) * 64 + sc16;
            *reinterpret_cast<short8*>(&Khi[skey][sc16])     = *reinterpret_cast<const short8*>(Khi_g + kb);
            *reinterpret_cast<short8*>(&Khi[skey][sc16 + 8]) = *reinterpret_cast<const short8*>(Khi_g + kb + 8);
            *reinterpret_cast<short8*>(&Klo[skey][sc16])     = *reinterpret_cast<const short8*>(Klo_g + kb);
            *reinterpret_cast<short8*>(&Klo[skey][sc16 + 8]) = *reinterpret_cast<const short8*>(Klo_g + kb + 8);
            const size_t vb = ((size_t)bh * 64 + skey) * 1024 + (size_t)kt * 64 + sc16; // skey = d row here
            *reinterpret_cast<short8*>(&Vt[skey][sc16])     = *reinterpret_cast<const short8*>(Vt_g + vb);
            *reinterpret_cast<short8*>(&Vt[skey][sc16 + 8]) = *reinterpret_cast<const short8*>(Vt_g + vb + 8);
        }
        __syncthreads();

        short8 kh[2][4], kl[2][4];
        #pragma unroll
        for (int s_ = 0; s_ < 2; ++s_)
            #pragma unroll
            for (int n = 0; n < 4; ++n) {
                kh[s_][n] = *reinterpret_cast<const short8*>(&Khi[n * 16 + fr][s_ * 32 + g8]);
                kl[s_][n] = *reinterpret_cast<const short8*>(&Klo[n * 16 + fr][s_ * 32 + g8]);
            }
        f32x4 S[4];
        #pragma unroll
        for (int n = 0; n < 4; ++n)
            #pragma unroll
            for (int r = 0; r < 4; ++r) S[n][r] = 0.0f;
        #pragma unroll
        for (int s_ = 0; s_ < 2; ++s_)
            #pragma unroll
            for (int n = 0; n < 4; ++n)
                S[n] = __builtin_amdgcn_mfma_f32_16x16x32_bf16(qhi[s_], kh[s_][n], S[n], 0, 0, 0);
        #pragma unroll
        for (int s_ = 0; s_ < 2; ++s_)
            #pragma unroll
            for (int n = 0; n < 4; ++n)
                S[n] = __builtin_amdgcn_mfma_f32_16x16x32_bf16(qhi[s_], kl[s_][n], S[n], 0, 0, 0);
        #pragma unroll
        for (int s_ = 0; s_ < 2; ++s_)
            #pragma unroll
            for (int n = 0; n < 4; ++n)
                S[n] = __builtin_amdgcn_mfma_f32_16x16x32_bf16(qlo[s_], kh[s_][n], S[n], 0, 0, 0);

        // online softmax: lane holds rows fq+r, cols n*16 + fr (per D-layout)
        float mt[4];
        #pragma unroll
        for (int r = 0; r < 4; ++r)
            mt[r] = fmaxf(fmaxf(S[0][r], S[1][r]), fmaxf(S[2][r], S[3][r])) * 8.0f;
        #pragma unroll
        for (int r = 0; r < 4; ++r) {
            mt[r] = fmaxf(mt[r], __shfl_xor(mt[r], 1));
            mt[r] = fmaxf(mt[r], __shfl_xor(mt[r], 2));
            mt[r] = fmaxf(mt[r], __shfl_xor(mt[r], 4));
            mt[r] = fmaxf(mt[r], __shfl_xor(mt[r], 8));
        }
        float P[4][4], rsum[4];
        #pragma unroll
        for (int r = 0; r < 4; ++r) {
            float mnew = fmaxf(mrun[r], mt[r]);
            float sf = __expf(mrun[r] - mnew);
            mrun[r] = mnew;
            rsum[r] = 0.0f;
            #pragma unroll
            for (int n = 0; n < 4; ++n) {
                float p = __expf(S[n][r] * 8.0f - mnew);
                P[n][r] = p;
                rsum[r] += p;
            }
            lrun[r] *= sf;
            #pragma unroll
            for (int nd = 0; nd < 4; ++nd) cacc[nd][r] *= sf;
        }
        #pragma unroll
        for (int r = 0; r < 4; ++r) {
            rsum[r] += __shfl_xor(rsum[r], 1);
            rsum[r] += __shfl_xor(rsum[r], 2);
            rsum[r] += __shfl_xor(rsum[r], 4);
            rsum[r] += __shfl_xor(rsum[r], 8);
            lrun[r] += rsum[r];
        }
        // P -> LDS (re-fragment for PV A-operand)
        #pragma unroll
        for (int n = 0; n < 4; ++n)
            #pragma unroll
            for (int r = 0; r < 4; ++r)
                Plds[wave][fq + r][n * 16 + fr] = f2bf(P[n][r]);
        __syncthreads();
        // PV: ctx += P @ V
        #pragma unroll
        for (int s_ = 0; s_ < 2; ++s_) {
            short8 pa = *reinterpret_cast<const short8*>(&Plds[wave][fr][s_ * 32 + g8]);
            #pragma unroll
            for (int nd = 0; nd < 4; ++nd) {
                short8 vb = *reinterpret_cast<const short8*>(&Vt[nd * 16 + fr][s_ * 32 + g8]);
                cacc[nd] = __builtin_amdgcn_mfma_f32_16x16x32_bf16(pa, vb, cacc[nd], 0, 0, 0);
            }
        }
    }
    // epilogue: ctx = cacc / l
    #pragma unroll
    for (int r = 0; r < 4; ++r) {
        const float inv = 1.0f / lrun[r];
        const int row = qt * 64 + wave * 16 + fq + r;
        unsigned short* cp = ctx + ((size_t)(b * 1024 + row)) * 1024 + h * 64;
        #pragma unroll
        for (int nd = 0; nd < 4; ++nd)
            cp[nd * 16 + fr] = f2bf(cacc[nd][r] * inv);
    }
}

// ---------------- launch ----------------
extern "C" void kernel_launch(void* const* d_in, const int* in_sizes, int n_in,
                              void* d_out, int out_size, void* d_ws, size_t ws_size,
                              hipStream_t stream) {
    const float* x      = (const float*)d_in[0];
    const float* norm_g = (const float*)d_in[1];
    const float* norm_b = (const float*)d_in[2];
    const float* w_qkv  = (const float*)d_in[3];
    const float* b_qkv  = (const float*)d_in[4];
    const float* w_proj = (const float*)d_in[5];
    const float* b_proj = (const float*)d_in[6];
    const float* w_fc1  = (const float*)d_in[7];
    const float* b_fc1  = (const float*)d_in[8];
    const float* w_fc2  = (const float*)d_in[9];
    const float* b_fc2  = (const float*)d_in[10];
    float* out = (float*)d_out;
    char* ws = (char*)d_ws;

    // workspace layout (~122 MB, dead-buffer overlap in region G)
    size_t off = 0;
    unsigned short* wqkvT3 = (unsigned short*)(ws + off); off += (size_t)3072 * 3072 * 2;
    unsigned short* wprojT = (unsigned short*)(ws + off); off += (size_t)1024 * 1024 * 2;
    unsigned short* wfc1T  = (unsigned short*)(ws + off); off += (size_t)4096 * 1024 * 2;
    unsigned short* wfc2T  = (unsigned short*)(ws + off); off += (size_t)1024 * 4096 * 2;
    unsigned short* ctxb   = (unsigned short*)(ws + off); off += (size_t)4096 * 1024 * 2;
    char* G = ws + off;
    // G region timeline:
    //   h3 [4096][3072] bf16 (25.17 MB) at G+0         : live ln -> qkv GEMMs
    //   Khi/Klo/Vt_g (3 x 8.39 MB = 25.17 MB) at G+0   : live kv_conv -> attn (overlap h3, dead)
    //   qkvf [4096][3072] f32 (50.3 MB) at G+25165824  : live qkv GEMMs -> attn
    //   fc1o [4096][4096] bf16 (33.5 MB) at G+0        : live fc1 -> fc2 (overlap Khi..+qkvf head)
    //   h2   [4096][1024] bf16 (8.4 MB) at G+33554432  : live ln2 -> fc1 (overlap qkvf tail)
    unsigned short* h3    = (unsigned short*)G;
    unsigned short* Khi_g = (unsigned short*)G;
    unsigned short* Klo_g = Khi_g + (size_t)64 * 1024 * 64;
    unsigned short* Vt_g  = Klo_g + (size_t)64 * 1024 * 64;
    float*          qkvf  = (float*)(G + (size_t)25165824);
    unsigned short* fc1o  = (unsigned short*)G;
    unsigned short* h2    = (unsigned short*)(G + (size_t)33554432);

    // weight prep
    transpose_w<1><<<dim3(96, 32),  256, 0, stream>>>(w_qkv,  wqkvT3, 1024, 3072);
    transpose_w<0><<<dim3(32, 32),  256, 0, stream>>>(w_proj, wprojT, 1024, 1024);
    transpose_w<0><<<dim3(128, 32), 256, 0, stream>>>(w_fc1,  wfc1T,  1024, 4096);
    transpose_w<0><<<dim3(32, 128), 256, 0, stream>>>(w_fc2,  wfc2T,  4096, 1024);

    // h = LN(x) (split3)
    ln_kernel<1><<<4096, 256, 0, stream>>>(x, norm_g, norm_b, h3);
    // q,k: split-precision GEMM (K'=3072) over cols 0..2047
    gemm_bt<0><<<dim3(16, 32), 256, 0, stream>>>(h3, wqkvT3, b_qkv, nullptr, qkvf,
                                                 4096, 2048, 3072, 3072, 3072, 3072);
    // v: plain bf16 GEMM (hi parts only, K=1024) over cols 2048..3071
    gemm_bt<0><<<dim3(8, 32), 256, 0, stream>>>(h3, wqkvT3 + (size_t)2048 * 3072, b_qkv + 2048,
                                                nullptr, qkvf + 2048,
                                                4096, 1024, 1024, 3072, 3072, 3072);

    // pre-convert K -> (hi,lo) bf16, V -> V^T bf16 (once, not per q-tile)
    kv_conv<<<dim3(16, 64), 256, 0, stream>>>(qkvf, Khi_g, Klo_g, Vt_g);

    // attention -> ctx (bf16)
    attn_kernel<<<dim3(16, 64), 256, 0, stream>>>(qkvf, Khi_g, Klo_g, Vt_g, ctxb);

    // x1 = x + ctx @ w_proj + b   (x1 lives in d_out)
    gemm_bt<1><<<dim3(8, 32), 256, 0, stream>>>(ctxb, wprojT, b_proj, x, out,
                                                4096, 1024, 1024, 1024, 1024, 1024);

    // h2 = LN(x1) ; fc1 = gelu(h2 @ w_fc1 + b) ; out = x1 + fc1 @ w_fc2 + b (in-place)
    ln_kernel<0><<<4096, 256, 0, stream>>>(out, norm_g, norm_b, h2);
    gemm_bt<2><<<dim3(32, 32), 256, 0, stream>>>(h2, wfc1T, b_fc1, nullptr, fc1o,
                                                 4096, 4096, 1024, 1024, 1024, 4096);
    gemm_bt<1><<<dim3(8, 32), 256, 0, stream>>>(fc1o, wfc2T, b_fc2, out, out,
                                                4096, 1024, 4096, 4096, 4096, 1024);
}

// Round 6
// 398.712 us; speedup vs baseline: 1.1206x; 1.0949x over previous
//
#include <hip/hip_runtime.h>
#include <hip/hip_bf16.h>

typedef __attribute__((ext_vector_type(8))) short short8;
typedef __attribute__((ext_vector_type(4))) float f32x4;

__device__ __forceinline__ unsigned short f2bf(float f) {
    __hip_bfloat16 h = __float2bfloat16(f);
    return *reinterpret_cast<unsigned short*>(&h);
}
__device__ __forceinline__ float bf2f(unsigned short u) {
    __hip_bfloat16 h = *reinterpret_cast<__hip_bfloat16*>(&u);
    return __bfloat162float(h);
}
__device__ __forceinline__ void hilo(float f, unsigned short& hi, unsigned short& lo) {
    hi = f2bf(f);
    lo = f2bf(f - bf2f(hi));
}

// async global->LDS, 16B per lane, wave-uniform LDS base + lane*16 dest
__device__ __forceinline__ void gld_lds16(const unsigned short* g, unsigned short* l) {
    __builtin_amdgcn_global_load_lds(
        (const __attribute__((address_space(1))) unsigned int*)g,
        (__attribute__((address_space(3))) unsigned int*)l, 16, 0, 0);
}

// ---------------- weight transpose + bf16 convert ----------------
// W [K][N] f32.  MODE 0: out[n*K + k] = bf16(W[k][n])
// MODE 1 (split3 for qkv): out row stride 3K: [n][k]=hi, [n][K+k]=lo, [n][2K+k]=hi
template<int MODE>
__global__ __launch_bounds__(256)
void transpose_w(const float* __restrict__ W, unsigned short* __restrict__ out, int K, int N) {
    __shared__ float tile[32][33];
    const int n0 = blockIdx.x * 32, k0 = blockIdx.y * 32;
    const int tid = threadIdx.x;
    const int r = tid >> 3, c4 = (tid & 7) << 2;
    float4 v = *reinterpret_cast<const float4*>(W + (size_t)(k0 + r) * N + n0 + c4);
    tile[r][c4 + 0] = v.x; tile[r][c4 + 1] = v.y;
    tile[r][c4 + 2] = v.z; tile[r][c4 + 3] = v.w;
    __syncthreads();
    const int n = n0 + r;
    if (MODE == 0) {
        ushort4 o;
        o.x = f2bf(tile[c4 + 0][r]); o.y = f2bf(tile[c4 + 1][r]);
        o.z = f2bf(tile[c4 + 2][r]); o.w = f2bf(tile[c4 + 3][r]);
        *reinterpret_cast<ushort4*>(out + (size_t)n * K + k0 + c4) = o;
    } else {
        ushort4 oh, ol;
        unsigned short hi, lo;
        hilo(tile[c4 + 0][r], hi, lo); oh.x = hi; ol.x = lo;
        hilo(tile[c4 + 1][r], hi, lo); oh.y = hi; ol.y = lo;
        hilo(tile[c4 + 2][r], hi, lo); oh.z = hi; ol.z = lo;
        hilo(tile[c4 + 3][r], hi, lo); oh.w = hi; ol.w = lo;
        size_t base = (size_t)n * 3 * K + k0 + c4;
        *reinterpret_cast<ushort4*>(out + base)         = oh;
        *reinterpret_cast<ushort4*>(out + base + K)     = ol;
        *reinterpret_cast<ushort4*>(out + base + 2 * K) = oh;
    }
}

// ---------------- LayerNorm ----------------
// MODE 0: out [row][1024] bf16.  MODE 1: out [row][3072]: hi, hi, lo (split3 A-layout)
template<int MODE>
__global__ __launch_bounds__(256)
void ln_kernel(const float* __restrict__ x, const float* __restrict__ gw,
               const float* __restrict__ bw, unsigned short* __restrict__ out) {
    const int row = blockIdx.x, tid = threadIdx.x;
    const float* xr = x + (size_t)row * 1024;
    float4 v = *reinterpret_cast<const float4*>(xr + tid * 4);
    float s = v.x + v.y + v.z + v.w;
    float sq = v.x * v.x + v.y * v.y + v.z * v.z + v.w * v.w;
    #pragma unroll
    for (int off = 1; off < 64; off <<= 1) {
        s  += __shfl_xor(s, off);
        sq += __shfl_xor(sq, off);
    }
    __shared__ float ps[4], pq[4];
    const int wave = tid >> 6;
    if ((tid & 63) == 0) { ps[wave] = s; pq[wave] = sq; }
    __syncthreads();
    s  = ps[0] + ps[1] + ps[2] + ps[3];
    sq = pq[0] + pq[1] + pq[2] + pq[3];
    const float mu = s * (1.0f / 1024.0f);
    const float var = sq * (1.0f / 1024.0f) - mu * mu;
    const float rs = rsqrtf(var + 1e-5f);
    float4 gv = *reinterpret_cast<const float4*>(gw + tid * 4);
    float4 bv = *reinterpret_cast<const float4*>(bw + tid * 4);
    float y[4];
    y[0] = (v.x - mu) * rs * gv.x + bv.x;
    y[1] = (v.y - mu) * rs * gv.y + bv.y;
    y[2] = (v.z - mu) * rs * gv.z + bv.z;
    y[3] = (v.w - mu) * rs * gv.w + bv.w;
    if (MODE == 0) {
        ushort4 o;
        o.x = f2bf(y[0]); o.y = f2bf(y[1]); o.z = f2bf(y[2]); o.w = f2bf(y[3]);
        *reinterpret_cast<ushort4*>(out + (size_t)row * 1024 + tid * 4) = o;
    } else {
        ushort4 oh, ol;
        unsigned short hi, lo;
        hilo(y[0], hi, lo); oh.x = hi; ol.x = lo;
        hilo(y[1], hi, lo); oh.y = hi; ol.y = lo;
        hilo(y[2], hi, lo); oh.z = hi; ol.z = lo;
        hilo(y[3], hi, lo); oh.w = hi; ol.w = lo;
        size_t base = (size_t)row * 3072 + tid * 4;
        *reinterpret_cast<ushort4*>(out + base)        = oh;
        *reinterpret_cast<ushort4*>(out + base + 1024) = oh;
        *reinterpret_cast<ushort4*>(out + base + 2048) = ol;
    }
}

// ---------------- GEMM: C = A @ B^T-input + bias (+epilogue) ----------------
// A [M][lda] bf16 row-major (cols 0..K), Bt [N][ldb] bf16 row-major.
// 128x128 tile, BK=32, 4 waves, global_load_lds staging into LINEAR double-buffered LDS.
// 2-phase prefetch: stage tile t+1 BEFORE computing tile t; ONE barrier per K-tile
// (compiler drains vmcnt at __syncthreads, so next-tile loads overlap current compute).
// EPI 0: f32 = acc+bias ; EPI 1: f32 = acc+bias+resid ; EPI 2: bf16 = gelu(acc+bias)
// EPI 3: raw f32 partial (split-K over blockIdx.z, K = chunk size, no bias)
template<int EPI>
__global__ __launch_bounds__(256)
void gemm_bt(const unsigned short* __restrict__ A, const unsigned short* __restrict__ Bt,
             const float* __restrict__ bias, const float* resid,
             void* Cout, int M, int N, int K, int lda, int ldb, int ldc) {
    __shared__ unsigned short As[2][128 * 32];   // row r at [buf][r*32], linear (global_load_lds)
    __shared__ unsigned short Bs[2][128 * 32];
    const int tid = threadIdx.x;
    const int wave = tid >> 6, lane = tid & 63;
    const int bm = blockIdx.y << 7, bn = blockIdx.x << 7;
    const int wr = (wave >> 1) << 6, wc = (wave & 1) << 6;
    const int fr = lane & 15, g8 = (lane >> 4) << 3, fq = (lane >> 4) << 2;
    const size_t koff = (EPI == 3) ? (size_t)blockIdx.z * K : 0;

    // staging map: wave w covers rows [w*32, w*32+32); per issue (16 rows = 1KB),
    // HW writes lds_base + lane*16B -> row w*32+i*16+(lane>>2), col-short (lane&3)*8.
    const int srow = (wave << 5) + (lane >> 2);
    const int scol = (lane & 3) << 3;
    const unsigned short* gA0 = A + (size_t)(bm + srow) * lda + scol + koff;
    const unsigned short* gA1 = gA0 + (size_t)16 * lda;
    const unsigned short* gB0 = Bt + (size_t)(bn + srow) * ldb + scol + koff;
    const unsigned short* gB1 = gB0 + (size_t)16 * ldb;

    f32x4 acc[4][4];
    #pragma unroll
    for (int m = 0; m < 4; ++m)
        #pragma unroll
        for (int n = 0; n < 4; ++n)
            #pragma unroll
            for (int r = 0; r < 4; ++r) acc[m][n][r] = 0.0f;

    auto stage = [&](int buf, int k0) {
        unsigned short* lA = &As[buf][wave << 10];   // wave-uniform base
        unsigned short* lB = &Bs[buf][wave << 10];
        gld_lds16(gA0 + k0, lA);
        gld_lds16(gA1 + k0, lA + 512);
        gld_lds16(gB0 + k0, lB);
        gld_lds16(gB1 + k0, lB + 512);
    };
    auto compute = [&](int buf) {
        short8 af[4], bfv[4];
        #pragma unroll
        for (int m = 0; m < 4; ++m)
            af[m] = *reinterpret_cast<const short8*>(&As[buf][(wr + m * 16 + fr) * 32 + g8]);
        #pragma unroll
        for (int n = 0; n < 4; ++n)
            bfv[n] = *reinterpret_cast<const short8*>(&Bs[buf][(wc + n * 16 + fr) * 32 + g8]);
        #pragma unroll
        for (int m = 0; m < 4; ++m)
            #pragma unroll
            for (int n = 0; n < 4; ++n)
                acc[m][n] = __builtin_amdgcn_mfma_f32_16x16x32_bf16(af[m], bfv[n], acc[m][n], 0, 0, 0);
    };

    const int nt = K >> 5;   // always even for our shapes (K multiple of 64)
    stage(0, 0);
    __syncthreads();          // drains vmcnt before anyone reads buf0
    int k0 = 32;
    for (int t = 0; t < nt - 2; t += 2) {
        stage(1, k0);         // issue next-tile loads (overlap with compute below)
        compute(0);
        __syncthreads();      // drains stage(1); all reads of buf0 complete
        stage(0, k0 + 32);
        compute(1);
        __syncthreads();
        k0 += 64;
    }
    stage(1, k0);
    compute(0);
    __syncthreads();
    compute(1);

    if (EPI == 3) {
        float* P = reinterpret_cast<float*>(Cout) + (size_t)blockIdx.z * (size_t)M * ldc;
        #pragma unroll
        for (int n = 0; n < 4; ++n) {
            const int col = bn + wc + n * 16 + fr;
            #pragma unroll
            for (int m = 0; m < 4; ++m)
                #pragma unroll
                for (int r = 0; r < 4; ++r) {
                    const int row = bm + wr + m * 16 + fq + r;
                    P[(size_t)row * ldc + col] = acc[m][n][r];
                }
        }
        return;
    }

    #pragma unroll
    for (int n = 0; n < 4; ++n) {
        const int col = bn + wc + n * 16 + fr;
        const float bc = bias[col];
        #pragma unroll
        for (int m = 0; m < 4; ++m) {
            #pragma unroll
            for (int r = 0; r < 4; ++r) {
                const int row = bm + wr + m * 16 + fq + r;
                const size_t idx = (size_t)row * ldc + col;
                float v = acc[m][n][r] + bc;
                if (EPI == 0) {
                    reinterpret_cast<float*>(Cout)[idx] = v;
                } else if (EPI == 1) {
                    reinterpret_cast<float*>(Cout)[idx] = v + resid[idx];
                } else {
                    float ge = 0.5f * v * (1.0f + erff(v * 0.70710678118654752f));
                    reinterpret_cast<unsigned short*>(Cout)[idx] = f2bf(ge);
                }
            }
        }
    }
}

// ---------------- split-K reduce (fc2): out = out + bias + p[0] + p[1] ----------------
// M=4096, N=1024 fixed; out is in-place residual (x1). Grid 4096 x 256, float4.
__global__ __launch_bounds__(256)
void red2_kernel(const float* __restrict__ p, const float* __restrict__ bias,
                 float* out) {
    const size_t MN = (size_t)4096 * 1024;
    const size_t i = ((size_t)blockIdx.x * 256 + threadIdx.x) * 4;
    float4 r  = *reinterpret_cast<const float4*>(out + i);
    float4 a  = *reinterpret_cast<const float4*>(p + i);
    float4 b  = *reinterpret_cast<const float4*>(p + MN + i);
    float4 bb = *reinterpret_cast<const float4*>(bias + (i & 1023));
    float4 o;
    o.x = r.x + a.x + b.x + bb.x;
    o.y = r.y + a.y + b.y + bb.y;
    o.z = r.z + a.z + b.z + bb.z;
    o.w = r.w + a.w + b.w + bb.w;
    *reinterpret_cast<float4*>(out + i) = o;
}

// ---------------- K/V pre-conversion ----------------
// qkv f32 [4096][3072] -> Khi/Klo [bh=64][key=1024][d=64] bf16, Vt [bh=64][d=64][key=1024] bf16
__global__ __launch_bounds__(256)
void kv_conv(const float* __restrict__ qkv, unsigned short* __restrict__ Khi_g,
             unsigned short* __restrict__ Klo_g, unsigned short* __restrict__ Vt_g) {
    __shared__ unsigned short VtT[64][72];
    const int kc = blockIdx.x;   // 16 chunks of 64 keys
    const int bh = blockIdx.y;   // b*16 + h
    const int b = bh >> 4, h = bh & 15;
    const int tid = threadIdx.x;
    const int key = tid >> 2, c16 = (tid & 3) << 4;
    const float* kp = qkv + ((size_t)(b * 1024 + kc * 64 + key)) * 3072 + h * 64 + c16;
    alignas(16) unsigned short khbuf[16], klbuf[16];
    #pragma unroll
    for (int j = 0; j < 16; j += 4) {
        float4 kv4 = *reinterpret_cast<const float4*>(kp + 1024 + j);
        float4 vv4 = *reinterpret_cast<const float4*>(kp + 2048 + j);
        float ks[4] = {kv4.x, kv4.y, kv4.z, kv4.w};
        float vs[4] = {vv4.x, vv4.y, vv4.z, vv4.w};
        #pragma unroll
        for (int c = 0; c < 4; ++c) {
            unsigned short hi, lo;
            hilo(ks[c], hi, lo);
            khbuf[j + c] = hi; klbuf[j + c] = lo;
            VtT[c16 + j + c][key] = f2bf(vs[c]);
        }
    }
    const size_t kb = ((size_t)bh * 1024 + kc * 64 + key) * 64 + c16;
    *reinterpret_cast<short8*>(Khi_g + kb)     = *reinterpret_cast<short8*>(&khbuf[0]);
    *reinterpret_cast<short8*>(Khi_g + kb + 8) = *reinterpret_cast<short8*>(&khbuf[8]);
    *reinterpret_cast<short8*>(Klo_g + kb)     = *reinterpret_cast<short8*>(&klbuf[0]);
    *reinterpret_cast<short8*>(Klo_g + kb + 8) = *reinterpret_cast<short8*>(&klbuf[8]);
    __syncthreads();
    const int d = tid >> 2;
    const size_t vb = ((size_t)bh * 64 + d) * 1024 + (size_t)kc * 64 + c16;
    *reinterpret_cast<short8*>(Vt_g + vb)     = *reinterpret_cast<const short8*>(&VtT[d][c16]);
    *reinterpret_cast<short8*>(Vt_g + vb + 8) = *reinterpret_cast<const short8*>(&VtT[d][c16 + 8]);
}

// ---------------- Flash attention ----------------
// q from qkvf f32 (hi/lo in reg), K/V from pre-converted bf16 buffers.
// scores = (q . k) * 8 ; split precision QK^T: S = qhi.khi + qhi.klo + qlo.khi
__global__ __launch_bounds__(256)
void attn_kernel(const float* __restrict__ qkv, const unsigned short* __restrict__ Khi_g,
                 const unsigned short* __restrict__ Klo_g, const unsigned short* __restrict__ Vt_g,
                 unsigned short* __restrict__ ctx) {
    __shared__ unsigned short Khi[64][72];
    __shared__ unsigned short Klo[64][72];
    __shared__ unsigned short Vt[64][72];
    __shared__ unsigned short Plds[4][16][72];
    const int qt = blockIdx.x;          // 16 q-tiles of 64 rows
    const int bh = blockIdx.y;          // b*16 + h
    const int b = bh >> 4, h = bh & 15;
    const int tid = threadIdx.x;
    const int wave = tid >> 6, lane = tid & 63;
    const int fr = lane & 15, g8 = (lane >> 4) << 3, fq = (lane >> 4) << 2;

    const int qrow = qt * 64 + wave * 16 + fr;
    const float* qp = qkv + ((size_t)(b * 1024 + qrow)) * 3072 + h * 64;
    short8 qhi[2], qlo[2];
    #pragma unroll
    for (int s_ = 0; s_ < 2; ++s_) {
        #pragma unroll
        for (int j = 0; j < 8; ++j) {
            float f = qp[s_ * 32 + g8 + j];
            unsigned short hi = f2bf(f);
            qhi[s_][j] = (short)hi;
            qlo[s_][j] = (short)f2bf(f - bf2f(hi));
        }
    }

    float mrun[4], lrun[4];
    f32x4 cacc[4];
    #pragma unroll
    for (int r = 0; r < 4; ++r) { mrun[r] = -3.0e38f; lrun[r] = 0.0f; }
    #pragma unroll
    for (int nd = 0; nd < 4; ++nd)
        #pragma unroll
        for (int r = 0; r < 4; ++r) cacc[nd][r] = 0.0f;

    const int skey = tid >> 2, sc16 = (tid & 3) << 4;

    for (int kt = 0; kt < 16; ++kt) {
        __syncthreads();
        {
            const size_t kb = ((size_t)bh * 1024 + kt * 64 + skey) * 64 + sc16;
            *reinterpret_cast<short8*>(&Khi[skey][sc16])     = *reinterpret_cast<const short8*>(Khi_g + kb);
            *reinterpret_cast<short8*>(&Khi[skey][sc16 + 8]) = *reinterpret_cast<const short8*>(Khi_g + kb + 8);
            *reinterpret_cast<short8*>(&Klo[skey][sc16])     = *reinterpret_cast<const short8*>(Klo_g + kb);
            *reinterpret_cast<short8*>(&Klo[skey][sc16 + 8]) = *reinterpret_cast<const short8*>(Klo_g + kb + 8);
            const size_t vb = ((size_t)bh * 64 + skey) * 1024 + (size_t)kt * 64 + sc16; // skey = d row
            *reinterpret_cast<short8*>(&Vt[skey][sc16])     = *reinterpret_cast<const short8*>(Vt_g + vb);
            *reinterpret_cast<short8*>(&Vt[skey][sc16 + 8]) = *reinterpret_cast<const short8*>(Vt_g + vb + 8);
        }
        __syncthreads();

        short8 kh[2][4], kl[2][4];
        #pragma unroll
        for (int s_ = 0; s_ < 2; ++s_)
            #pragma unroll
            for (int n = 0; n < 4; ++n) {
                kh[s_][n] = *reinterpret_cast<const short8*>(&Khi[n * 16 + fr][s_ * 32 + g8]);
                kl[s_][n] = *reinterpret_cast<const short8*>(&Klo[n * 16 + fr][s_ * 32 + g8]);
            }
        f32x4 S[4];
        #pragma unroll
        for (int n = 0; n < 4; ++n)
            #pragma unroll
            for (int r = 0; r < 4; ++r) S[n][r] = 0.0f;
        #pragma unroll
        for (int s_ = 0; s_ < 2; ++s_)
            #pragma unroll
            for (int n = 0; n < 4; ++n)
                S[n] = __builtin_amdgcn_mfma_f32_16x16x32_bf16(qhi[s_], kh[s_][n], S[n], 0, 0, 0);
        #pragma unroll
        for (int s_ = 0; s_ < 2; ++s_)
            #pragma unroll
            for (int n = 0; n < 4; ++n)
                S[n] = __builtin_amdgcn_mfma_f32_16x16x32_bf16(qhi[s_], kl[s_][n], S[n], 0, 0, 0);
        #pragma unroll
        for (int s_ = 0; s_ < 2; ++s_)
            #pragma unroll
            for (int n = 0; n < 4; ++n)
                S[n] = __builtin_amdgcn_mfma_f32_16x16x32_bf16(qlo[s_], kh[s_][n], S[n], 0, 0, 0);

        float mt[4];
        #pragma unroll
        for (int r = 0; r < 4; ++r)
            mt[r] = fmaxf(fmaxf(S[0][r], S[1][r]), fmaxf(S[2][r], S[3][r])) * 8.0f;
        #pragma unroll
        for (int r = 0; r < 4; ++r) {
            mt[r] = fmaxf(mt[r], __shfl_xor(mt[r], 1));
            mt[r] = fmaxf(mt[r], __shfl_xor(mt[r], 2));
            mt[r] = fmaxf(mt[r], __shfl_xor(mt[r], 4));
            mt[r] = fmaxf(mt[r], __shfl_xor(mt[r], 8));
        }
        float P[4][4], rsum[4];
        #pragma unroll
        for (int r = 0; r < 4; ++r) {
            float mnew = fmaxf(mrun[r], mt[r]);
            float sf = __expf(mrun[r] - mnew);
            mrun[r] = mnew;
            rsum[r] = 0.0f;
            #pragma unroll
            for (int n = 0; n < 4; ++n) {
                float p = __expf(S[n][r] * 8.0f - mnew);
                P[n][r] = p;
                rsum[r] += p;
            }
            lrun[r] *= sf;
            #pragma unroll
            for (int nd = 0; nd < 4; ++nd) cacc[nd][r] *= sf;
        }
        #pragma unroll
        for (int r = 0; r < 4; ++r) {
            rsum[r] += __shfl_xor(rsum[r], 1);
            rsum[r] += __shfl_xor(rsum[r], 2);
            rsum[r] += __shfl_xor(rsum[r], 4);
            rsum[r] += __shfl_xor(rsum[r], 8);
            lrun[r] += rsum[r];
        }
        #pragma unroll
        for (int n = 0; n < 4; ++n)
            #pragma unroll
            for (int r = 0; r < 4; ++r)
                Plds[wave][fq + r][n * 16 + fr] = f2bf(P[n][r]);
        __syncthreads();
        #pragma unroll
        for (int s_ = 0; s_ < 2; ++s_) {
            short8 pa = *reinterpret_cast<const short8*>(&Plds[wave][fr][s_ * 32 + g8]);
            #pragma unroll
            for (int nd = 0; nd < 4; ++nd) {
                short8 vb = *reinterpret_cast<const short8*>(&Vt[nd * 16 + fr][s_ * 32 + g8]);
                cacc[nd] = __builtin_amdgcn_mfma_f32_16x16x32_bf16(pa, vb, cacc[nd], 0, 0, 0);
            }
        }
    }
    #pragma unroll
    for (int r = 0; r < 4; ++r) {
        const float inv = 1.0f / lrun[r];
        const int row = qt * 64 + wave * 16 + fq + r;
        unsigned short* cp = ctx + ((size_t)(b * 1024 + row)) * 1024 + h * 64;
        #pragma unroll
        for (int nd = 0; nd < 4; ++nd)
            cp[nd * 16 + fr] = f2bf(cacc[nd][r] * inv);
    }
}

// ---------------- launch ----------------
extern "C" void kernel_launch(void* const* d_in, const int* in_sizes, int n_in,
                              void* d_out, int out_size, void* d_ws, size_t ws_size,
                              hipStream_t stream) {
    const float* x      = (const float*)d_in[0];
    const float* norm_g = (const float*)d_in[1];
    const float* norm_b = (const float*)d_in[2];
    const float* w_qkv  = (const float*)d_in[3];
    const float* b_qkv  = (const float*)d_in[4];
    const float* w_proj = (const float*)d_in[5];
    const float* b_proj = (const float*)d_in[6];
    const float* w_fc1  = (const float*)d_in[7];
    const float* b_fc1  = (const float*)d_in[8];
    const float* w_fc2  = (const float*)d_in[9];
    const float* b_fc2  = (const float*)d_in[10];
    float* out = (float*)d_out;
    char* ws = (char*)d_ws;

    // workspace layout (~116 MB, dead-buffer overlap in region G)
    size_t off = 0;
    unsigned short* wqkvT3 = (unsigned short*)(ws + off); off += (size_t)3072 * 3072 * 2;
    unsigned short* wprojT = (unsigned short*)(ws + off); off += (size_t)1024 * 1024 * 2;
    unsigned short* wfc1T  = (unsigned short*)(ws + off); off += (size_t)4096 * 1024 * 2;
    unsigned short* wfc2T  = (unsigned short*)(ws + off); off += (size_t)1024 * 4096 * 2;
    unsigned short* ctxb   = (unsigned short*)(ws + off); off += (size_t)4096 * 1024 * 2;
    char* G = ws + off;
    // G region timeline:
    //   h3 [4096][3072] bf16 (25.17 MB) at G+0           : ln -> qkv GEMMs
    //   Khi/Klo/Vt_g (3 x 8.39 = 25.17 MB) at G+0        : kv_conv -> attn (overlaps dead h3)
    //   qkvf [4096][3072] f32 (50.3 MB) at G+25165824    : qkv GEMMs -> attn
    //   fc1o [4096][4096] bf16 (33.5 MB) at G+0          : fc1 -> fc2 (overlaps Khi..+qkvf head)
    //   h2   [4096][1024] bf16 (8.4 MB) at G+33554432    : ln2 -> fc1 (overlaps qkvf tail)
    //   fc2p [2][4096][1024] f32 (33.5 MB) at G+41943040 : fc2 partials -> red2 (overlaps qkvf tail)
    unsigned short* h3    = (unsigned short*)G;
    unsigned short* Khi_g = (unsigned short*)G;
    unsigned short* Klo_g = Khi_g + (size_t)64 * 1024 * 64;
    unsigned short* Vt_g  = Klo_g + (size_t)64 * 1024 * 64;
    float*          qkvf  = (float*)(G + (size_t)25165824);
    unsigned short* fc1o  = (unsigned short*)G;
    unsigned short* h2    = (unsigned short*)(G + (size_t)33554432);
    float*          fc2p  = (float*)(G + (size_t)41943040);

    // weight prep
    transpose_w<1><<<dim3(96, 32),  256, 0, stream>>>(w_qkv,  wqkvT3, 1024, 3072);
    transpose_w<0><<<dim3(32, 32),  256, 0, stream>>>(w_proj, wprojT, 1024, 1024);
    transpose_w<0><<<dim3(128, 32), 256, 0, stream>>>(w_fc1,  wfc1T,  1024, 4096);
    transpose_w<0><<<dim3(32, 128), 256, 0, stream>>>(w_fc2,  wfc2T,  4096, 1024);

    // h = LN(x) (split3)
    ln_kernel<1><<<4096, 256, 0, stream>>>(x, norm_g, norm_b, h3);
    // q,k: split-precision GEMM (K'=3072) over cols 0..2047
    gemm_bt<0><<<dim3(16, 32), 256, 0, stream>>>(h3, wqkvT3, b_qkv, nullptr, qkvf,
                                                 4096, 2048, 3072, 3072, 3072, 3072);
    // v: plain bf16 GEMM (hi parts only, K=1024) over cols 2048..3071
    gemm_bt<0><<<dim3(8, 32), 256, 0, stream>>>(h3, wqkvT3 + (size_t)2048 * 3072, b_qkv + 2048,
                                                nullptr, qkvf + 2048,
                                                4096, 1024, 1024, 3072, 3072, 3072);

    // pre-convert K -> (hi,lo) bf16, V -> V^T bf16
    kv_conv<<<dim3(16, 64), 256, 0, stream>>>(qkvf, Khi_g, Klo_g, Vt_g);

    // attention -> ctx (bf16)
    attn_kernel<<<dim3(16, 64), 256, 0, stream>>>(qkvf, Khi_g, Klo_g, Vt_g, ctxb);

    // x1 = x + ctx @ w_proj + b   (x1 lives in d_out)
    gemm_bt<1><<<dim3(8, 32), 256, 0, stream>>>(ctxb, wprojT, b_proj, x, out,
                                                4096, 1024, 1024, 1024, 1024, 1024);

    // h2 = LN(x1) ; fc1 = gelu(h2 @ w_fc1 + b)
    ln_kernel<0><<<4096, 256, 0, stream>>>(out, norm_g, norm_b, h2);
    gemm_bt<2><<<dim3(32, 32), 256, 0, stream>>>(h2, wfc1T, b_fc1, nullptr, fc1o,
                                                 4096, 4096, 1024, 1024, 1024, 4096);
    // fc2: split-K=2 partials (K chunk 2048 each), then reduce + bias + residual (in-place)
    gemm_bt<3><<<dim3(8, 32, 2), 256, 0, stream>>>(fc1o, wfc2T, nullptr, nullptr, fc2p,
                                                   4096, 1024, 2048, 4096, 4096, 1024);
    red2_kernel<<<4096, 256, 0, stream>>>(fc2p, b_fc2, out);
}

// Round 7
// 306.937 us; speedup vs baseline: 1.4557x; 1.2990x over previous
//
#include <hip/hip_runtime.h>
#include <hip/hip_bf16.h>

typedef __attribute__((ext_vector_type(8))) short short8;
typedef __attribute__((ext_vector_type(8))) _Float16 half8;
typedef __attribute__((ext_vector_type(4))) float f32x4;

__device__ __forceinline__ unsigned short f2h(float f) {
    _Float16 h = (_Float16)f;
    return *reinterpret_cast<unsigned short*>(&h);
}
__device__ __forceinline__ float h2f(unsigned short u) {
    _Float16 h = *reinterpret_cast<_Float16*>(&u);
    return (float)h;
}

// async global->LDS, 16B per lane, wave-uniform LDS base + lane*16 dest
__device__ __forceinline__ void gld_lds16(const unsigned short* g, unsigned short* l) {
    __builtin_amdgcn_global_load_lds(
        (const __attribute__((address_space(1))) unsigned int*)g,
        (__attribute__((address_space(3))) unsigned int*)l, 16, 0, 0);
}

// ---------------- weight transpose + fp16 convert ----------------
// W [K][N] f32 -> out [n*K + k] = fp16(W[k][n])
__global__ __launch_bounds__(256)
void transpose_w(const float* __restrict__ W, unsigned short* __restrict__ out, int K, int N) {
    __shared__ float tile[32][33];
    const int n0 = blockIdx.x * 32, k0 = blockIdx.y * 32;
    const int tid = threadIdx.x;
    const int r = tid >> 3, c4 = (tid & 7) << 2;
    float4 v = *reinterpret_cast<const float4*>(W + (size_t)(k0 + r) * N + n0 + c4);
    tile[r][c4 + 0] = v.x; tile[r][c4 + 1] = v.y;
    tile[r][c4 + 2] = v.z; tile[r][c4 + 3] = v.w;
    __syncthreads();
    const int n = n0 + r;
    ushort4 o;
    o.x = f2h(tile[c4 + 0][r]); o.y = f2h(tile[c4 + 1][r]);
    o.z = f2h(tile[c4 + 2][r]); o.w = f2h(tile[c4 + 3][r]);
    *reinterpret_cast<ushort4*>(out + (size_t)n * K + k0 + c4) = o;
}

// ---------------- LayerNorm -> fp16 [row][1024] ----------------
__global__ __launch_bounds__(256)
void ln_kernel(const float* __restrict__ x, const float* __restrict__ gw,
               const float* __restrict__ bw, unsigned short* __restrict__ out) {
    const int row = blockIdx.x, tid = threadIdx.x;
    const float* xr = x + (size_t)row * 1024;
    float4 v = *reinterpret_cast<const float4*>(xr + tid * 4);
    float s = v.x + v.y + v.z + v.w;
    float sq = v.x * v.x + v.y * v.y + v.z * v.z + v.w * v.w;
    #pragma unroll
    for (int off = 1; off < 64; off <<= 1) {
        s  += __shfl_xor(s, off);
        sq += __shfl_xor(sq, off);
    }
    __shared__ float ps[4], pq[4];
    const int wave = tid >> 6;
    if ((tid & 63) == 0) { ps[wave] = s; pq[wave] = sq; }
    __syncthreads();
    s  = ps[0] + ps[1] + ps[2] + ps[3];
    sq = pq[0] + pq[1] + pq[2] + pq[3];
    const float mu = s * (1.0f / 1024.0f);
    const float var = sq * (1.0f / 1024.0f) - mu * mu;
    const float rs = rsqrtf(var + 1e-5f);
    float4 gv = *reinterpret_cast<const float4*>(gw + tid * 4);
    float4 bv = *reinterpret_cast<const float4*>(bw + tid * 4);
    ushort4 o;
    o.x = f2h((v.x - mu) * rs * gv.x + bv.x);
    o.y = f2h((v.y - mu) * rs * gv.y + bv.y);
    o.z = f2h((v.z - mu) * rs * gv.z + bv.z);
    o.w = f2h((v.w - mu) * rs * gv.w + bv.w);
    *reinterpret_cast<ushort4*>(out + (size_t)row * 1024 + tid * 4) = o;
}

// ---------------- GEMM: C = A @ B^T-input + bias (+epilogue), all fp16 ----------------
// A [M][lda] fp16 row-major (cols 0..K), Bt [N][ldb] fp16 row-major.
// 128x128 tile, BK=32, 4 waves, global_load_lds into LINEAR double-buffered LDS,
// 2-phase prefetch (stage t+1 before compute t, one barrier per K-tile).
// EPI 0: fp16 = acc+bias ; EPI 1: f32 = acc+bias+resid ; EPI 2: fp16 = gelu(acc+bias)
// EPI 3: raw f32 partial (split-K over blockIdx.z, K = chunk size, no bias)
template<int EPI>
__global__ __launch_bounds__(256)
void gemm_bt(const unsigned short* __restrict__ A, const unsigned short* __restrict__ Bt,
             const float* __restrict__ bias, const float* resid,
             void* Cout, int M, int N, int K, int lda, int ldb, int ldc) {
    __shared__ unsigned short As[2][128 * 32];   // row r at [buf][r*32], linear (global_load_lds)
    __shared__ unsigned short Bs[2][128 * 32];
    const int tid = threadIdx.x;
    const int wave = tid >> 6, lane = tid & 63;
    const int bm = blockIdx.y << 7, bn = blockIdx.x << 7;
    const int wr = (wave >> 1) << 6, wc = (wave & 1) << 6;
    const int fr = lane & 15, g8 = (lane >> 4) << 3, fq = (lane >> 4) << 2;
    const size_t koff = (EPI == 3) ? (size_t)blockIdx.z * K : 0;

    const int srow = (wave << 5) + (lane >> 2);
    const int scol = (lane & 3) << 3;
    const unsigned short* gA0 = A + (size_t)(bm + srow) * lda + scol + koff;
    const unsigned short* gA1 = gA0 + (size_t)16 * lda;
    const unsigned short* gB0 = Bt + (size_t)(bn + srow) * ldb + scol + koff;
    const unsigned short* gB1 = gB0 + (size_t)16 * ldb;

    f32x4 acc[4][4];
    #pragma unroll
    for (int m = 0; m < 4; ++m)
        #pragma unroll
        for (int n = 0; n < 4; ++n)
            #pragma unroll
            for (int r = 0; r < 4; ++r) acc[m][n][r] = 0.0f;

    auto stage = [&](int buf, int k0) {
        unsigned short* lA = &As[buf][wave << 10];
        unsigned short* lB = &Bs[buf][wave << 10];
        gld_lds16(gA0 + k0, lA);
        gld_lds16(gA1 + k0, lA + 512);
        gld_lds16(gB0 + k0, lB);
        gld_lds16(gB1 + k0, lB + 512);
    };
    auto compute = [&](int buf) {
        half8 af[4], bfv[4];
        #pragma unroll
        for (int m = 0; m < 4; ++m)
            af[m] = *reinterpret_cast<const half8*>(&As[buf][(wr + m * 16 + fr) * 32 + g8]);
        #pragma unroll
        for (int n = 0; n < 4; ++n)
            bfv[n] = *reinterpret_cast<const half8*>(&Bs[buf][(wc + n * 16 + fr) * 32 + g8]);
        #pragma unroll
        for (int m = 0; m < 4; ++m)
            #pragma unroll
            for (int n = 0; n < 4; ++n)
                acc[m][n] = __builtin_amdgcn_mfma_f32_16x16x32_f16(af[m], bfv[n], acc[m][n], 0, 0, 0);
    };

    const int nt = K >> 5;   // even for all our shapes
    stage(0, 0);
    __syncthreads();
    int k0 = 32;
    for (int t = 0; t < nt - 2; t += 2) {
        stage(1, k0);
        compute(0);
        __syncthreads();
        stage(0, k0 + 32);
        compute(1);
        __syncthreads();
        k0 += 64;
    }
    stage(1, k0);
    compute(0);
    __syncthreads();
    compute(1);

    if (EPI == 3) {
        float* P = reinterpret_cast<float*>(Cout) + (size_t)blockIdx.z * (size_t)M * ldc;
        #pragma unroll
        for (int n = 0; n < 4; ++n) {
            const int col = bn + wc + n * 16 + fr;
            #pragma unroll
            for (int m = 0; m < 4; ++m)
                #pragma unroll
                for (int r = 0; r < 4; ++r) {
                    const int row = bm + wr + m * 16 + fq + r;
                    P[(size_t)row * ldc + col] = acc[m][n][r];
                }
        }
        return;
    }

    #pragma unroll
    for (int n = 0; n < 4; ++n) {
        const int col = bn + wc + n * 16 + fr;
        const float bc = bias[col];
        #pragma unroll
        for (int m = 0; m < 4; ++m) {
            #pragma unroll
            for (int r = 0; r < 4; ++r) {
                const int row = bm + wr + m * 16 + fq + r;
                const size_t idx = (size_t)row * ldc + col;
                float v = acc[m][n][r] + bc;
                if (EPI == 0) {
                    reinterpret_cast<unsigned short*>(Cout)[idx] = f2h(v);
                } else if (EPI == 1) {
                    reinterpret_cast<float*>(Cout)[idx] = v + resid[idx];
                } else {
                    float ge = 0.5f * v * (1.0f + erff(v * 0.70710678118654752f));
                    reinterpret_cast<unsigned short*>(Cout)[idx] = f2h(ge);
                }
            }
        }
    }
}

// ---------------- split-K reduce (fc2): out = out + bias + p[0] + p[1] ----------------
__global__ __launch_bounds__(256)
void red2_kernel(const float* __restrict__ p, const float* __restrict__ bias,
                 float* out) {
    const size_t MN = (size_t)4096 * 1024;
    const size_t i = ((size_t)blockIdx.x * 256 + threadIdx.x) * 4;
    float4 r  = *reinterpret_cast<const float4*>(out + i);
    float4 a  = *reinterpret_cast<const float4*>(p + i);
    float4 b  = *reinterpret_cast<const float4*>(p + MN + i);
    float4 bb = *reinterpret_cast<const float4*>(bias + (i & 1023));
    float4 o;
    o.x = r.x + a.x + b.x + bb.x;
    o.y = r.y + a.y + b.y + bb.y;
    o.z = r.z + a.z + b.z + bb.z;
    o.w = r.w + a.w + b.w + bb.w;
    *reinterpret_cast<float4*>(out + i) = o;
}

// ---------------- K/V compaction ----------------
// qkv16 fp16 [4096][3072] -> K_g [bh][key=1024][d=64] fp16 scaled x8 (exact pow2),
//                            Vt_g [bh][d=64][key=1024] fp16
__global__ __launch_bounds__(256)
void kv_conv(const unsigned short* __restrict__ qkv16, unsigned short* __restrict__ K_g,
             unsigned short* __restrict__ Vt_g) {
    __shared__ unsigned short VtT[64][72];
    const int kc = blockIdx.x;   // 16 chunks of 64 keys
    const int bh = blockIdx.y;   // b*16 + h
    const int b = bh >> 4, h = bh & 15;
    const int tid = threadIdx.x;
    const int key = tid >> 2, c16 = (tid & 3) << 4;
    const unsigned short* kp = qkv16 + ((size_t)(b * 1024 + kc * 64 + key)) * 3072 + 1024 + h * 64 + c16;
    alignas(16) unsigned short kbuf[16];
    #pragma unroll
    for (int j = 0; j < 16; j += 8) {
        short8 k8 = *reinterpret_cast<const short8*>(kp + j);
        short8 v8 = *reinterpret_cast<const short8*>(kp + 1024 + j);   // v is 1024 cols after k
        #pragma unroll
        for (int c = 0; c < 8; ++c) {
            kbuf[j + c] = f2h(8.0f * h2f((unsigned short)k8[c]));      // fold score scale into K
            VtT[c16 + j + c][key] = (unsigned short)v8[c];
        }
    }
    const size_t kb = ((size_t)bh * 1024 + kc * 64 + key) * 64 + c16;
    *reinterpret_cast<short8*>(K_g + kb)     = *reinterpret_cast<short8*>(&kbuf[0]);
    *reinterpret_cast<short8*>(K_g + kb + 8) = *reinterpret_cast<short8*>(&kbuf[8]);
    __syncthreads();
    const int d = tid >> 2;
    const size_t vb = ((size_t)bh * 64 + d) * 1024 + (size_t)kc * 64 + c16;
    *reinterpret_cast<short8*>(Vt_g + vb)     = *reinterpret_cast<const short8*>(&VtT[d][c16]);
    *reinterpret_cast<short8*>(Vt_g + vb + 8) = *reinterpret_cast<const short8*>(&VtT[d][c16 + 8]);
}

// ---------------- Flash attention (all fp16, single-pass QK^T) ----------------
// q from qkv16 fp16; K pre-scaled by 8 so S = (q.k)*8 directly.
__global__ __launch_bounds__(256)
void attn_kernel(const unsigned short* __restrict__ qkv16,
                 const unsigned short* __restrict__ K_g,
                 const unsigned short* __restrict__ Vt_g,
                 unsigned short* __restrict__ ctx) {
    __shared__ unsigned short Kh[64][72];
    __shared__ unsigned short Vt[64][72];
    __shared__ unsigned short Plds[4][16][72];
    const int qt = blockIdx.x;          // 16 q-tiles of 64 rows
    const int bh = blockIdx.y;          // b*16 + h
    const int b = bh >> 4, h = bh & 15;
    const int tid = threadIdx.x;
    const int wave = tid >> 6, lane = tid & 63;
    const int fr = lane & 15, g8 = (lane >> 4) << 3, fq = (lane >> 4) << 2;

    const int qrow = qt * 64 + wave * 16 + fr;
    const unsigned short* qp = qkv16 + ((size_t)(b * 1024 + qrow)) * 3072 + h * 64;
    half8 qf[2];
    qf[0] = *reinterpret_cast<const half8*>(qp + g8);
    qf[1] = *reinterpret_cast<const half8*>(qp + 32 + g8);

    float mrun[4], lrun[4];
    f32x4 cacc[4];
    #pragma unroll
    for (int r = 0; r < 4; ++r) { mrun[r] = -3.0e38f; lrun[r] = 0.0f; }
    #pragma unroll
    for (int nd = 0; nd < 4; ++nd)
        #pragma unroll
        for (int r = 0; r < 4; ++r) cacc[nd][r] = 0.0f;

    const int skey = tid >> 2, sc16 = (tid & 3) << 4;

    for (int kt = 0; kt < 16; ++kt) {
        __syncthreads();
        {
            const size_t kb = ((size_t)bh * 1024 + kt * 64 + skey) * 64 + sc16;
            *reinterpret_cast<short8*>(&Kh[skey][sc16])     = *reinterpret_cast<const short8*>(K_g + kb);
            *reinterpret_cast<short8*>(&Kh[skey][sc16 + 8]) = *reinterpret_cast<const short8*>(K_g + kb + 8);
            const size_t vb = ((size_t)bh * 64 + skey) * 1024 + (size_t)kt * 64 + sc16; // skey = d row
            *reinterpret_cast<short8*>(&Vt[skey][sc16])     = *reinterpret_cast<const short8*>(Vt_g + vb);
            *reinterpret_cast<short8*>(&Vt[skey][sc16 + 8]) = *reinterpret_cast<const short8*>(Vt_g + vb + 8);
        }
        __syncthreads();

        f32x4 S[4];
        #pragma unroll
        for (int n = 0; n < 4; ++n)
            #pragma unroll
            for (int r = 0; r < 4; ++r) S[n][r] = 0.0f;
        #pragma unroll
        for (int s_ = 0; s_ < 2; ++s_)
            #pragma unroll
            for (int n = 0; n < 4; ++n) {
                half8 kh = *reinterpret_cast<const half8*>(&Kh[n * 16 + fr][s_ * 32 + g8]);
                S[n] = __builtin_amdgcn_mfma_f32_16x16x32_f16(qf[s_], kh, S[n], 0, 0, 0);
            }

        // online softmax: lane holds rows fq+r, cols n*16+fr (D-layout); S already x8-scaled
        float mt[4];
        #pragma unroll
        for (int r = 0; r < 4; ++r)
            mt[r] = fmaxf(fmaxf(S[0][r], S[1][r]), fmaxf(S[2][r], S[3][r]));
        #pragma unroll
        for (int r = 0; r < 4; ++r) {
            mt[r] = fmaxf(mt[r], __shfl_xor(mt[r], 1));
            mt[r] = fmaxf(mt[r], __shfl_xor(mt[r], 2));
            mt[r] = fmaxf(mt[r], __shfl_xor(mt[r], 4));
            mt[r] = fmaxf(mt[r], __shfl_xor(mt[r], 8));
        }
        float P[4][4], rsum[4];
        #pragma unroll
        for (int r = 0; r < 4; ++r) {
            float mnew = fmaxf(mrun[r], mt[r]);
            float sf = __expf(mrun[r] - mnew);
            mrun[r] = mnew;
            rsum[r] = 0.0f;
            #pragma unroll
            for (int n = 0; n < 4; ++n) {
                float p = __expf(S[n][r] - mnew);
                P[n][r] = p;
                rsum[r] += p;
            }
            lrun[r] *= sf;
            #pragma unroll
            for (int nd = 0; nd < 4; ++nd) cacc[nd][r] *= sf;
        }
        #pragma unroll
        for (int r = 0; r < 4; ++r) {
            rsum[r] += __shfl_xor(rsum[r], 1);
            rsum[r] += __shfl_xor(rsum[r], 2);
            rsum[r] += __shfl_xor(rsum[r], 4);
            rsum[r] += __shfl_xor(rsum[r], 8);
            lrun[r] += rsum[r];
        }
        // P -> per-wave LDS slab (same-wave RAW; compiler orders via lgkmcnt, no barrier)
        #pragma unroll
        for (int n = 0; n < 4; ++n)
            #pragma unroll
            for (int r = 0; r < 4; ++r)
                Plds[wave][fq + r][n * 16 + fr] = f2h(P[n][r]);
        #pragma unroll
        for (int s_ = 0; s_ < 2; ++s_) {
            half8 pa = *reinterpret_cast<const half8*>(&Plds[wave][fr][s_ * 32 + g8]);
            #pragma unroll
            for (int nd = 0; nd < 4; ++nd) {
                half8 vb8 = *reinterpret_cast<const half8*>(&Vt[nd * 16 + fr][s_ * 32 + g8]);
                cacc[nd] = __builtin_amdgcn_mfma_f32_16x16x32_f16(pa, vb8, cacc[nd], 0, 0, 0);
            }
        }
    }
    #pragma unroll
    for (int r = 0; r < 4; ++r) {
        const float inv = 1.0f / lrun[r];
        const int row = qt * 64 + wave * 16 + fq + r;
        unsigned short* cp = ctx + ((size_t)(b * 1024 + row)) * 1024 + h * 64;
        #pragma unroll
        for (int nd = 0; nd < 4; ++nd)
            cp[nd * 16 + fr] = f2h(cacc[nd][r] * inv);
    }
}

// ---------------- launch ----------------
extern "C" void kernel_launch(void* const* d_in, const int* in_sizes, int n_in,
                              void* d_out, int out_size, void* d_ws, size_t ws_size,
                              hipStream_t stream) {
    const float* x      = (const float*)d_in[0];
    const float* norm_g = (const float*)d_in[1];
    const float* norm_b = (const float*)d_in[2];
    const float* w_qkv  = (const float*)d_in[3];
    const float* b_qkv  = (const float*)d_in[4];
    const float* w_proj = (const float*)d_in[5];
    const float* b_proj = (const float*)d_in[6];
    const float* w_fc1  = (const float*)d_in[7];
    const float* b_fc1  = (const float*)d_in[8];
    const float* w_fc2  = (const float*)d_in[9];
    const float* b_fc2  = (const float*)d_in[10];
    float* out = (float*)d_out;
    char* ws = (char*)d_ws;

    // workspace layout (~117 MB, dead-buffer overlap in region G)
    size_t off = 0;
    unsigned short* wqkvT  = (unsigned short*)(ws + off); off += (size_t)3072 * 1024 * 2;
    unsigned short* wprojT = (unsigned short*)(ws + off); off += (size_t)1024 * 1024 * 2;
    unsigned short* wfc1T  = (unsigned short*)(ws + off); off += (size_t)4096 * 1024 * 2;
    unsigned short* wfc2T  = (unsigned short*)(ws + off); off += (size_t)1024 * 4096 * 2;
    unsigned short* ctxb   = (unsigned short*)(ws + off); off += (size_t)4096 * 1024 * 2;
    char* G = ws + off;
    // G region timeline (offsets in bytes):
    //   h1     [4096][1024] fp16 ( 8.4 MB) at G+0        : ln -> qkv GEMM
    //   qkv16  [4096][3072] fp16 (25.2 MB) at G+8388608  : qkv GEMM -> attn (q) / kv_conv
    //   K_g    [64][1024][64] fp16 (8.4 MB) at G+0       : kv_conv -> attn (overlaps dead h1)
    //   Vt_g   [64][64][1024] fp16 (8.4 MB) at G+33554432: kv_conv -> attn
    //   fc1o   [4096][4096] fp16 (33.5 MB) at G+0        : fc1 -> fc2 (overlaps dead h1/K_g/qkv16)
    //   h2     [4096][1024] fp16 ( 8.4 MB) at G+41943040 : ln2 -> fc1
    //   fc2p   [2][4096][1024] f32 (33.5 MB) at G+50331648 : fc2 partials -> red2
    unsigned short* h1    = (unsigned short*)G;
    unsigned short* qkv16 = (unsigned short*)(G + (size_t)8388608);
    unsigned short* K_g   = (unsigned short*)G;
    unsigned short* Vt_g  = (unsigned short*)(G + (size_t)33554432);
    unsigned short* fc1o  = (unsigned short*)G;
    unsigned short* h2    = (unsigned short*)(G + (size_t)41943040);
    float*          fc2p  = (float*)(G + (size_t)50331648);

    // weight prep (all fp16, plain transpose)
    transpose_w<<<dim3(96, 32),  256, 0, stream>>>(w_qkv,  wqkvT,  1024, 3072);
    transpose_w<<<dim3(32, 32),  256, 0, stream>>>(w_proj, wprojT, 1024, 1024);
    transpose_w<<<dim3(128, 32), 256, 0, stream>>>(w_fc1,  wfc1T,  1024, 4096);
    transpose_w<<<dim3(32, 128), 256, 0, stream>>>(w_fc2,  wfc2T,  4096, 1024);

    // h1 = LN(x) fp16 ; qkv16 = fp16(h1 @ w_qkv + b)  (single plain GEMM, K=1024)
    ln_kernel<<<4096, 256, 0, stream>>>(x, norm_g, norm_b, h1);
    gemm_bt<0><<<dim3(24, 32), 256, 0, stream>>>(h1, wqkvT, b_qkv, nullptr, qkv16,
                                                 4096, 3072, 1024, 1024, 1024, 3072);

    // compact K (x8-scaled) and V^T
    kv_conv<<<dim3(16, 64), 256, 0, stream>>>(qkv16, K_g, Vt_g);

    // attention -> ctx (fp16)
    attn_kernel<<<dim3(16, 64), 256, 0, stream>>>(qkv16, K_g, Vt_g, ctxb);

    // x1 = x + ctx @ w_proj + b   (x1 lives in d_out)
    gemm_bt<1><<<dim3(8, 32), 256, 0, stream>>>(ctxb, wprojT, b_proj, x, out,
                                                4096, 1024, 1024, 1024, 1024, 1024);

    // h2 = LN(x1) ; fc1 = gelu(h2 @ w_fc1 + b)
    ln_kernel<<<4096, 256, 0, stream>>>(out, norm_g, norm_b, h2);
    gemm_bt<2><<<dim3(32, 32), 256, 0, stream>>>(h2, wfc1T, b_fc1, nullptr, fc1o,
                                                 4096, 4096, 1024, 1024, 1024, 4096);
    // fc2: split-K=2 partials, then reduce + bias + residual (in-place on out)
    gemm_bt<3><<<dim3(8, 32, 2), 256, 0, stream>>>(fc1o, wfc2T, nullptr, nullptr, fc2p,
                                                   4096, 1024, 2048, 4096, 4096, 1024);
    red2_kernel<<<4096, 256, 0, stream>>>(fc2p, b_fc2, out);
}